// Round 1
// baseline (1257.301 us; speedup 1.0000x reference)
//
#include <hip/hip_runtime.h>

#define HIDDEN 128

// ---------------------------------------------------------------- degree count
__global__ __launch_bounds__(256) void count_kernel(const int* __restrict__ col,
                                                    int* __restrict__ deg, int E) {
    int e = blockIdx.x * 256 + threadIdx.x;
    if (e < E) atomicAdd(&deg[col[e]], 1);
}

// ------------------------------------------------- single-block exclusive scan
// offsets[i] = sum_{k<i} deg[k]; also cursor copy and dinv = rsqrt(deg+1)
__global__ __launch_bounds__(1024) void scan_kernel(const int* __restrict__ deg,
                                                    int* __restrict__ offsets,
                                                    int* __restrict__ cursor,
                                                    float* __restrict__ dinv, int N) {
    __shared__ int sums[1024];
    int t = threadIdx.x;
    int chunk = (N + 1023) >> 10;
    int lo = t * chunk;
    int hi = min(lo + chunk, N);
    int s = 0;
    for (int i = lo; i < hi; ++i) s += deg[i];
    sums[t] = s;
    __syncthreads();
    // Hillis-Steele inclusive scan
    for (int d = 1; d < 1024; d <<= 1) {
        int v = (t >= d) ? sums[t - d] : 0;
        __syncthreads();
        sums[t] += v;
        __syncthreads();
    }
    int run = (t > 0) ? sums[t - 1] : 0;   // exclusive prefix of this chunk
    for (int i = lo; i < hi; ++i) {
        offsets[i] = run;
        cursor[i]  = run;
        int d = deg[i];
        dinv[i] = rsqrtf((float)(d + 1));  // +1 self loop
        run += d;
    }
    if (t == 1023) offsets[N] = run;       // == E
}

// ------------------------------------------------------------------- CSR fill
__global__ __launch_bounds__(256) void fill_kernel(const int* __restrict__ row,
                                                   const int* __restrict__ col,
                                                   int* __restrict__ cursor,
                                                   int* __restrict__ sorted_r, int E) {
    int e = blockIdx.x * 256 + threadIdx.x;
    if (e < E) {
        int c = col[e];
        int p = atomicAdd(&cursor[c], 1);
        sorted_r[p] = row[e];
    }
}

// ------------------------------------------------------------- input GEMM K=11
__global__ __launch_bounds__(256) void gemm_in(const float* __restrict__ x,
                                               const float* __restrict__ W1,
                                               float* __restrict__ out, int N) {
    int i = blockIdx.x * 2 + (threadIdx.x >> 7);
    int j = threadIdx.x & 127;
    if (i >= N) return;
    float acc = 0.f;
#pragma unroll
    for (int c = 0; c < 11; ++c) acc += x[(size_t)i * 11 + c] * W1[c * HIDDEN + j];
    out[(size_t)i * HIDDEN + j] = acc;
}

// ------------------------------------------------- GEMM: out = relu(H+b) @ W
// H [N,128] (pre-activation), W [128,128], act fused on load.
__global__ __launch_bounds__(256) void gemm128(const float* __restrict__ H,
                                               const float* __restrict__ bias,
                                               const float* __restrict__ W,
                                               float* __restrict__ out, int N) {
    __shared__ float Hlds[16][HIDDEN];   // 8 KB
    int t = threadIdx.x;
    int rowbase = blockIdx.x * 16;
    // stage H tile with fused bias+relu
    for (int q = t; q < 16 * HIDDEN; q += 256) {
        int r = q >> 7, k = q & 127;
        int gr = rowbase + r;
        float v = 0.f;
        if (gr < N) v = fmaxf(H[(size_t)gr * HIDDEN + k] + bias[k], 0.f);
        Hlds[r][k] = v;
    }
    __syncthreads();
    int j  = t & 127;
    int rb = t >> 7;              // 0 or 1
    float acc[8] = {0.f, 0.f, 0.f, 0.f, 0.f, 0.f, 0.f, 0.f};
#pragma unroll 4
    for (int k = 0; k < HIDDEN; ++k) {
        float wv = W[k * HIDDEN + j];   // coalesced, L2-hot (64 KB)
#pragma unroll
        for (int m = 0; m < 8; ++m) acc[m] += Hlds[rb + 2 * m][k] * wv;
    }
#pragma unroll
    for (int m = 0; m < 8; ++m) {
        int gr = rowbase + rb + 2 * m;
        if (gr < N) out[(size_t)gr * HIDDEN + j] = acc[m];
    }
}

// ------------------------------------------------- aggregation: gather by CSR
// dst[c] = dinv[c] * ( sum_{r in in(c)} dinv[r]*src[r] + dinv[c]*src[c] )
__global__ __launch_bounds__(256) void agg_kernel(const float* __restrict__ src,
                                                  float* __restrict__ dst,
                                                  const int* __restrict__ offsets,
                                                  const int* __restrict__ sorted_r,
                                                  const float* __restrict__ dinv, int N) {
    int wid  = (blockIdx.x * 256 + threadIdx.x) >> 6;   // one wave per node
    int lane = threadIdx.x & 63;
    if (wid >= N) return;
    int c = wid;
    int beg = offsets[c], end = offsets[c + 1];
    float dc = dinv[c];
    const float2* srcp = (const float2*)src;
    float2 v = srcp[(size_t)c * 64 + lane];             // self loop
    float ax = dc * v.x, ay = dc * v.y;
    for (int idx = beg; idx < end; ++idx) {
        int r = sorted_r[idx];
        float dr = dinv[r];
        float2 u = srcp[(size_t)r * 64 + lane];
        ax += dr * u.x;
        ay += dr * u.y;
    }
    ((float2*)dst)[(size_t)c * 64 + lane] = make_float2(ax * dc, ay * dc);
}

// -------------------------------------- pooling (mean over sorted batch) + head
__global__ __launch_bounds__(256) void pool_head_kernel(const float* __restrict__ h,
                                                        const int* __restrict__ batch,
                                                        const float* __restrict__ b4,
                                                        const float* __restrict__ Wd1,
                                                        const float* __restrict__ bd1,
                                                        const float* __restrict__ Wd2,
                                                        const float* __restrict__ bd2,
                                                        const float* __restrict__ Wo,
                                                        const float* __restrict__ bo,
                                                        float* __restrict__ out, int N) {
    int g = blockIdx.x;
    int t = threadIdx.x;
    int j = t & 127, part = t >> 7;    // 2 parts
    __shared__ float p0[128], p1[128], sA[128], sB[128];
    __shared__ float red[256];
    __shared__ int s_lo, s_hi;
    if (t == 0) {
        int lo = 0, hi = N;
        while (lo < hi) { int m = (lo + hi) >> 1; if (batch[m] < g) lo = m + 1; else hi = m; }
        s_lo = lo;
        lo = 0; hi = N;
        while (lo < hi) { int m = (lo + hi) >> 1; if (batch[m] < g + 1) lo = m + 1; else hi = m; }
        s_hi = lo;
    }
    __syncthreads();
    int beg = s_lo, end = s_hi;
    // mean pool (+ fused b4); 2 row-parts
    float acc = 0.f;
    for (int i = beg + part; i < end; i += 2) acc += h[(size_t)i * HIDDEN + j];
    if (part) p1[j] = acc; else p0[j] = acc;
    __syncthreads();
    if (part == 0) {
        int cnt = end - beg;
        sA[j] = (cnt > 0) ? (p0[j] + p1[j]) / (float)cnt + b4[j] : 0.f;
    }
    __syncthreads();
    // dense layer 1: sB = relu(sA @ Wd1 + bd1), k split across parts
    {
        float a = 0.f;
        int k0 = part * 64;
#pragma unroll 4
        for (int kk = 0; kk < 64; ++kk) { int k = k0 + kk; a += sA[k] * Wd1[k * HIDDEN + j]; }
        if (part) p1[j] = a; else p0[j] = a;
        __syncthreads();
        if (part == 0) sB[j] = fmaxf(p0[j] + p1[j] + bd1[j], 0.f);
        __syncthreads();
    }
    // dense layer 2: sA = relu(sB @ Wd2 + bd2)
    {
        float a = 0.f;
        int k0 = part * 64;
#pragma unroll 4
        for (int kk = 0; kk < 64; ++kk) { int k = k0 + kk; a += sB[k] * Wd2[k * HIDDEN + j]; }
        if (part) p1[j] = a; else p0[j] = a;
        __syncthreads();
        if (part == 0) sA[j] = fmaxf(p0[j] + p1[j] + bd2[j], 0.f);
        __syncthreads();
    }
    // output: out[g] = sum_j sA[j]*Wo[j] + bo
    red[t] = (part == 0) ? sA[j] * Wo[j] : 0.f;
    __syncthreads();
    for (int s = 128; s > 0; s >>= 1) {
        if (t < s) red[t] += red[t + s];
        __syncthreads();
    }
    if (t == 0) out[g] = red[0] + bo[0];
}

// ============================================================================
extern "C" void kernel_launch(void* const* d_in, const int* in_sizes, int n_in,
                              void* d_out, int out_size, void* d_ws, size_t ws_size,
                              hipStream_t stream) {
    const float* x   = (const float*)d_in[0];
    const int*   ei  = (const int*)d_in[1];
    const int*   bat = (const int*)d_in[2];
    const float* W1  = (const float*)d_in[3];
    const float* b1  = (const float*)d_in[4];
    const float* W2  = (const float*)d_in[5];
    const float* b2  = (const float*)d_in[6];
    const float* W4  = (const float*)d_in[7];
    const float* b4  = (const float*)d_in[8];
    const float* Wd1 = (const float*)d_in[9];
    const float* bd1 = (const float*)d_in[10];
    const float* Wd2 = (const float*)d_in[11];
    const float* bd2 = (const float*)d_in[12];
    const float* Wo  = (const float*)d_in[13];
    const float* bo  = (const float*)d_in[14];
    float* out = (float*)d_out;

    const int N = in_sizes[0] / 11;
    const int E = in_sizes[1] / 2;
    const int* row = ei;
    const int* col = ei + E;

    // workspace carve-up
    size_t off = 0;
    auto carve = [&](size_t bytes) {
        void* p = (char*)d_ws + off;
        off += (bytes + 255) & ~(size_t)255;
        return p;
    };
    float* bufA     = (float*)carve((size_t)N * HIDDEN * 4);
    float* bufB     = (float*)carve((size_t)N * HIDDEN * 4);
    int*   deg      = (int*)carve((size_t)N * 4);
    int*   offsets  = (int*)carve((size_t)(N + 1) * 4);
    int*   cursor   = (int*)carve((size_t)N * 4);
    float* dinv     = (float*)carve((size_t)N * 4);
    int*   sorted_r = (int*)carve((size_t)E * 4);
    (void)ws_size; (void)n_in; (void)out_size;

    // ---- build CSR (once per call; reused by all 3 layers)
    hipMemsetAsync(deg, 0, (size_t)N * 4, stream);
    count_kernel<<<(E + 255) / 256, 256, 0, stream>>>(col, deg, E);
    scan_kernel<<<1, 1024, 0, stream>>>(deg, offsets, cursor, dinv, N);
    fill_kernel<<<(E + 255) / 256, 256, 0, stream>>>(row, col, cursor, sorted_r, E);

    int aggBlocks  = (N + 3) / 4;          // 4 waves (nodes) per 256-thread block
    int gemmBlocks = (N + 15) / 16;

    // ---- layer 1
    gemm_in<<<(N + 1) / 2, 256, 0, stream>>>(x, W1, bufA, N);
    agg_kernel<<<aggBlocks, 256, 0, stream>>>(bufA, bufB, offsets, sorted_r, dinv, N);
    // ---- layer 2 (relu(bufB+b1) fused into GEMM load)
    gemm128<<<gemmBlocks, 256, 0, stream>>>(bufB, b1, W2, bufA, N);
    agg_kernel<<<aggBlocks, 256, 0, stream>>>(bufA, bufB, offsets, sorted_r, dinv, N);
    // ---- layer 3
    gemm128<<<gemmBlocks, 256, 0, stream>>>(bufB, b2, W4, bufA, N);
    agg_kernel<<<aggBlocks, 256, 0, stream>>>(bufA, bufB, offsets, sorted_r, dinv, N);
    // ---- pool + dense head (b4 folded into pooled mean)
    pool_head_kernel<<<128, 256, 0, stream>>>(bufB, bat, b4, Wd1, bd1, Wd2, bd2,
                                              Wo, bo, out, N);
}

// Round 2
// 984.618 us; speedup vs baseline: 1.2769x; 1.2769x over previous
//
#include <hip/hip_runtime.h>

#define HIDDEN 128

// ---------------------------------------------------------------- degree count
__global__ __launch_bounds__(256) void count_kernel(const int* __restrict__ col,
                                                    int* __restrict__ deg, int E) {
    int e = blockIdx.x * 256 + threadIdx.x;
    if (e < E) atomicAdd(&deg[col[e]], 1);
}

// ----------------------------------------------------- scan phase 1: block sums
__global__ __launch_bounds__(256) void scan_blocksums(const int* __restrict__ deg,
                                                      int* __restrict__ bsums, int N) {
    __shared__ int red[256];
    int t = threadIdx.x;
    int base = blockIdx.x * 1024 + t * 4;
    int s = 0;
    if (base + 3 < N) {
        int4 v = *(const int4*)(deg + base);
        s = v.x + v.y + v.z + v.w;
    } else {
        for (int k = 0; k < 4; ++k) if (base + k < N) s += deg[base + k];
    }
    red[t] = s;
    __syncthreads();
    for (int d = 128; d > 0; d >>= 1) {
        if (t < d) red[t] += red[t + d];
        __syncthreads();
    }
    if (t == 0) bsums[blockIdx.x] = red[0];
}

// ------------------------------------- scan phase 2: write offsets/cursor/dinv
__global__ __launch_bounds__(256) void scan_write(const int* __restrict__ deg,
                                                  const int* __restrict__ bsums,
                                                  int* __restrict__ offsets,
                                                  int* __restrict__ cursor,
                                                  float* __restrict__ dinv,
                                                  int N, int E) {
    __shared__ int incl[256];
    __shared__ int red[256];
    __shared__ int s_boff;
    int t = threadIdx.x;
    int base = blockIdx.x * 1024 + t * 4;
    int d0 = 0, d1 = 0, d2 = 0, d3 = 0;
    if (base + 3 < N) {
        int4 v = *(const int4*)(deg + base);
        d0 = v.x; d1 = v.y; d2 = v.z; d3 = v.w;
    } else {
        if (base + 0 < N) d0 = deg[base + 0];
        if (base + 1 < N) d1 = deg[base + 1];
        if (base + 2 < N) d2 = deg[base + 2];
        if (base + 3 < N) d3 = deg[base + 3];
    }
    int mysum = d0 + d1 + d2 + d3;
    incl[t] = mysum;
    // block offset: sum of bsums[0 .. blockIdx.x)
    int b = 0;
    for (int i = t; i < blockIdx.x; i += 256) b += bsums[i];
    red[t] = b;
    __syncthreads();
    for (int d = 128; d > 0; d >>= 1) {
        if (t < d) red[t] += red[t + d];
        __syncthreads();
    }
    if (t == 0) s_boff = red[0];
    // Hillis-Steele inclusive scan of thread sums
    for (int d = 1; d < 256; d <<= 1) {
        int v = (t >= d) ? incl[t - d] : 0;
        __syncthreads();
        incl[t] += v;
        __syncthreads();
    }
    int run = s_boff + incl[t] - mysum;   // exclusive prefix for this thread
    if (base + 0 < N) { offsets[base + 0] = run; cursor[base + 0] = run; dinv[base + 0] = rsqrtf((float)(d0 + 1)); run += d0; }
    if (base + 1 < N) { offsets[base + 1] = run; cursor[base + 1] = run; dinv[base + 1] = rsqrtf((float)(d1 + 1)); run += d1; }
    if (base + 2 < N) { offsets[base + 2] = run; cursor[base + 2] = run; dinv[base + 2] = rsqrtf((float)(d2 + 1)); run += d2; }
    if (base + 3 < N) { offsets[base + 3] = run; cursor[base + 3] = run; dinv[base + 3] = rsqrtf((float)(d3 + 1)); run += d3; }
    if (blockIdx.x == 0 && t == 0) offsets[N] = E;
}

// ------------------------------------------------------------------- CSR fill
__global__ __launch_bounds__(256) void fill_kernel(const int* __restrict__ row,
                                                   const int* __restrict__ col,
                                                   int* __restrict__ cursor,
                                                   int* __restrict__ sorted_r, int E) {
    int e = blockIdx.x * 256 + threadIdx.x;
    if (e < E) {
        int c = col[e];
        int p = atomicAdd(&cursor[c], 1);
        sorted_r[p] = row[e];
    }
}

// ------------------------------------------------------------- input GEMM K=11
__global__ __launch_bounds__(256) void gemm_in(const float* __restrict__ x,
                                               const float* __restrict__ W1,
                                               float* __restrict__ out, int N) {
    int i = blockIdx.x * 2 + (threadIdx.x >> 7);
    int j = threadIdx.x & 127;
    if (i >= N) return;
    float acc = 0.f;
#pragma unroll
    for (int c = 0; c < 11; ++c) acc += x[(size_t)i * 11 + c] * W1[c * HIDDEN + j];
    out[(size_t)i * HIDDEN + j] = acc;
}

// ------------------------------------------------- GEMM: out = relu(H+b) @ W
// H [N,128] (pre-activation), W [128,128], act fused on load.
__global__ __launch_bounds__(256) void gemm128(const float* __restrict__ H,
                                               const float* __restrict__ bias,
                                               const float* __restrict__ W,
                                               float* __restrict__ out, int N) {
    __shared__ float Hlds[16][HIDDEN];   // 8 KB
    int t = threadIdx.x;
    int rowbase = blockIdx.x * 16;
    for (int q = t; q < 16 * HIDDEN; q += 256) {
        int r = q >> 7, k = q & 127;
        int gr = rowbase + r;
        float v = 0.f;
        if (gr < N) v = fmaxf(H[(size_t)gr * HIDDEN + k] + bias[k], 0.f);
        Hlds[r][k] = v;
    }
    __syncthreads();
    int j  = t & 127;
    int rb = t >> 7;              // 0 or 1
    float acc[8] = {0.f, 0.f, 0.f, 0.f, 0.f, 0.f, 0.f, 0.f};
#pragma unroll 4
    for (int k = 0; k < HIDDEN; ++k) {
        float wv = W[k * HIDDEN + j];   // coalesced, L2-hot (64 KB)
#pragma unroll
        for (int m = 0; m < 8; ++m) acc[m] += Hlds[rb + 2 * m][k] * wv;
    }
#pragma unroll
    for (int m = 0; m < 8; ++m) {
        int gr = rowbase + rb + 2 * m;
        if (gr < N) out[(size_t)gr * HIDDEN + j] = acc[m];
    }
}

// ------------------------------------------------- aggregation: gather by CSR
// dst[c] = dinv[c] * ( sum_{r in in(c)} dinv[r]*src[r] + dinv[c]*src[c] )
__global__ __launch_bounds__(256) void agg_kernel(const float* __restrict__ src,
                                                  float* __restrict__ dst,
                                                  const int* __restrict__ offsets,
                                                  const int* __restrict__ sorted_r,
                                                  const float* __restrict__ dinv, int N) {
    int wid  = (blockIdx.x * 256 + threadIdx.x) >> 6;   // one wave per node
    int lane = threadIdx.x & 63;
    if (wid >= N) return;
    int c = wid;
    int beg = offsets[c], end = offsets[c + 1];
    float dc = dinv[c];
    const float2* srcp = (const float2*)src;
    float2 v = srcp[(size_t)c * 64 + lane];             // self loop
    float ax = dc * v.x, ay = dc * v.y;
    for (int idx = beg; idx < end; ++idx) {
        int r = sorted_r[idx];
        float dr = dinv[r];
        float2 u = srcp[(size_t)r * 64 + lane];
        ax += dr * u.x;
        ay += dr * u.y;
    }
    ((float2*)dst)[(size_t)c * 64 + lane] = make_float2(ax * dc, ay * dc);
}

// -------------------------------------- pooling (mean over sorted batch) + head
__global__ __launch_bounds__(256) void pool_head_kernel(const float* __restrict__ h,
                                                        const int* __restrict__ batch,
                                                        const float* __restrict__ b4,
                                                        const float* __restrict__ Wd1,
                                                        const float* __restrict__ bd1,
                                                        const float* __restrict__ Wd2,
                                                        const float* __restrict__ bd2,
                                                        const float* __restrict__ Wo,
                                                        const float* __restrict__ bo,
                                                        float* __restrict__ out, int N) {
    int g = blockIdx.x;
    int t = threadIdx.x;
    int j = t & 127, part = t >> 7;    // 2 parts
    __shared__ float p0[128], p1[128], sA[128], sB[128];
    __shared__ float red[256];
    __shared__ int s_lo, s_hi;
    if (t == 0) {
        int lo = 0, hi = N;
        while (lo < hi) { int m = (lo + hi) >> 1; if (batch[m] < g) lo = m + 1; else hi = m; }
        s_lo = lo;
        lo = 0; hi = N;
        while (lo < hi) { int m = (lo + hi) >> 1; if (batch[m] < g + 1) lo = m + 1; else hi = m; }
        s_hi = lo;
    }
    __syncthreads();
    int beg = s_lo, end = s_hi;
    float acc = 0.f;
    for (int i = beg + part; i < end; i += 2) acc += h[(size_t)i * HIDDEN + j];
    if (part) p1[j] = acc; else p0[j] = acc;
    __syncthreads();
    if (part == 0) {
        int cnt = end - beg;
        sA[j] = (cnt > 0) ? (p0[j] + p1[j]) / (float)cnt + b4[j] : 0.f;
    }
    __syncthreads();
    {
        float a = 0.f;
        int k0 = part * 64;
#pragma unroll 4
        for (int kk = 0; kk < 64; ++kk) { int k = k0 + kk; a += sA[k] * Wd1[k * HIDDEN + j]; }
        if (part) p1[j] = a; else p0[j] = a;
        __syncthreads();
        if (part == 0) sB[j] = fmaxf(p0[j] + p1[j] + bd1[j], 0.f);
        __syncthreads();
    }
    {
        float a = 0.f;
        int k0 = part * 64;
#pragma unroll 4
        for (int kk = 0; kk < 64; ++kk) { int k = k0 + kk; a += sB[k] * Wd2[k * HIDDEN + j]; }
        if (part) p1[j] = a; else p0[j] = a;
        __syncthreads();
        if (part == 0) sA[j] = fmaxf(p0[j] + p1[j] + bd2[j], 0.f);
        __syncthreads();
    }
    red[t] = (part == 0) ? sA[j] * Wo[j] : 0.f;
    __syncthreads();
    for (int s = 128; s > 0; s >>= 1) {
        if (t < s) red[t] += red[t + s];
        __syncthreads();
    }
    if (t == 0) out[g] = red[0] + bo[0];
}

// ============================================================================
extern "C" void kernel_launch(void* const* d_in, const int* in_sizes, int n_in,
                              void* d_out, int out_size, void* d_ws, size_t ws_size,
                              hipStream_t stream) {
    const float* x   = (const float*)d_in[0];
    const int*   ei  = (const int*)d_in[1];
    const int*   bat = (const int*)d_in[2];
    const float* W1  = (const float*)d_in[3];
    const float* b1  = (const float*)d_in[4];
    const float* W2  = (const float*)d_in[5];
    const float* b2  = (const float*)d_in[6];
    const float* W4  = (const float*)d_in[7];
    const float* b4  = (const float*)d_in[8];
    const float* Wd1 = (const float*)d_in[9];
    const float* bd1 = (const float*)d_in[10];
    const float* Wd2 = (const float*)d_in[11];
    const float* bd2 = (const float*)d_in[12];
    const float* Wo  = (const float*)d_in[13];
    const float* bo  = (const float*)d_in[14];
    float* out = (float*)d_out;

    const int N = in_sizes[0] / 11;
    const int E = in_sizes[1] / 2;
    const int* row = ei;
    const int* col = ei + E;

    size_t off = 0;
    auto carve = [&](size_t bytes) {
        void* p = (char*)d_ws + off;
        off += (bytes + 255) & ~(size_t)255;
        return p;
    };
    float* bufA     = (float*)carve((size_t)N * HIDDEN * 4);
    float* bufB     = (float*)carve((size_t)N * HIDDEN * 4);
    int*   deg      = (int*)carve((size_t)N * 4);
    int*   offsets  = (int*)carve((size_t)(N + 1) * 4);
    int*   cursor   = (int*)carve((size_t)N * 4);
    float* dinv     = (float*)carve((size_t)N * 4);
    int*   sorted_r = (int*)carve((size_t)E * 4);
    int*   bsums    = (int*)carve((size_t)1024 * 4);
    (void)ws_size; (void)n_in; (void)out_size;

    // ---- build CSR (once per call; reused by all 3 layers)
    hipMemsetAsync(deg, 0, (size_t)N * 4, stream);
    count_kernel<<<(E + 255) / 256, 256, 0, stream>>>(col, deg, E);
    int scanBlocks = (N + 1023) / 1024;
    scan_blocksums<<<scanBlocks, 256, 0, stream>>>(deg, bsums, N);
    scan_write<<<scanBlocks, 256, 0, stream>>>(deg, bsums, offsets, cursor, dinv, N, E);
    fill_kernel<<<(E + 255) / 256, 256, 0, stream>>>(row, col, cursor, sorted_r, E);

    int aggBlocks  = (N + 3) / 4;          // 4 waves (nodes) per 256-thread block
    int gemmBlocks = (N + 15) / 16;

    // ---- layer 1
    gemm_in<<<(N + 1) / 2, 256, 0, stream>>>(x, W1, bufA, N);
    agg_kernel<<<aggBlocks, 256, 0, stream>>>(bufA, bufB, offsets, sorted_r, dinv, N);
    // ---- layer 2 (relu(bufB+b1) fused into GEMM load)
    gemm128<<<gemmBlocks, 256, 0, stream>>>(bufB, b1, W2, bufA, N);
    agg_kernel<<<aggBlocks, 256, 0, stream>>>(bufA, bufB, offsets, sorted_r, dinv, N);
    // ---- layer 3
    gemm128<<<gemmBlocks, 256, 0, stream>>>(bufB, b2, W4, bufA, N);
    agg_kernel<<<aggBlocks, 256, 0, stream>>>(bufA, bufB, offsets, sorted_r, dinv, N);
    // ---- pool + dense head (b4 folded into pooled mean)
    pool_head_kernel<<<128, 256, 0, stream>>>(bufB, bat, b4, Wd1, bd1, Wd2, bd2,
                                              Wo, bo, out, N);
}

// Round 3
// 714.477 us; speedup vs baseline: 1.7598x; 1.3781x over previous
//
#include <hip/hip_runtime.h>

#define HIDDEN 128

// ---------------------------------------------------------------- degree count
__global__ __launch_bounds__(256) void count_kernel(const int* __restrict__ col,
                                                    int* __restrict__ deg, int E) {
    int e = blockIdx.x * 256 + threadIdx.x;
    if (e < E) atomicAdd(&deg[col[e]], 1);
}

// ----------------------------------------------------- scan phase 1: block sums
__global__ __launch_bounds__(256) void scan_blocksums(const int* __restrict__ deg,
                                                      int* __restrict__ bsums, int N) {
    __shared__ int red[256];
    int t = threadIdx.x;
    int base = blockIdx.x * 1024 + t * 4;
    int s = 0;
    if (base + 3 < N) {
        int4 v = *(const int4*)(deg + base);
        s = v.x + v.y + v.z + v.w;
    } else {
        for (int k = 0; k < 4; ++k) if (base + k < N) s += deg[base + k];
    }
    red[t] = s;
    __syncthreads();
    for (int d = 128; d > 0; d >>= 1) {
        if (t < d) red[t] += red[t + d];
        __syncthreads();
    }
    if (t == 0) bsums[blockIdx.x] = red[0];
}

// ------------------------------------- scan phase 2: write offsets/cursor/dinv
__global__ __launch_bounds__(256) void scan_write(const int* __restrict__ deg,
                                                  const int* __restrict__ bsums,
                                                  int* __restrict__ offsets,
                                                  int* __restrict__ cursor,
                                                  float* __restrict__ dinv,
                                                  int N, int E) {
    __shared__ int incl[256];
    __shared__ int red[256];
    __shared__ int s_boff;
    int t = threadIdx.x;
    int base = blockIdx.x * 1024 + t * 4;
    int d0 = 0, d1 = 0, d2 = 0, d3 = 0;
    if (base + 3 < N) {
        int4 v = *(const int4*)(deg + base);
        d0 = v.x; d1 = v.y; d2 = v.z; d3 = v.w;
    } else {
        if (base + 0 < N) d0 = deg[base + 0];
        if (base + 1 < N) d1 = deg[base + 1];
        if (base + 2 < N) d2 = deg[base + 2];
        if (base + 3 < N) d3 = deg[base + 3];
    }
    int mysum = d0 + d1 + d2 + d3;
    incl[t] = mysum;
    int b = 0;
    for (int i = t; i < blockIdx.x; i += 256) b += bsums[i];
    red[t] = b;
    __syncthreads();
    for (int d = 128; d > 0; d >>= 1) {
        if (t < d) red[t] += red[t + d];
        __syncthreads();
    }
    if (t == 0) s_boff = red[0];
    for (int d = 1; d < 256; d <<= 1) {
        int v = (t >= d) ? incl[t - d] : 0;
        __syncthreads();
        incl[t] += v;
        __syncthreads();
    }
    int run = s_boff + incl[t] - mysum;
    if (base + 0 < N) { offsets[base + 0] = run; cursor[base + 0] = run; dinv[base + 0] = rsqrtf((float)(d0 + 1)); run += d0; }
    if (base + 1 < N) { offsets[base + 1] = run; cursor[base + 1] = run; dinv[base + 1] = rsqrtf((float)(d1 + 1)); run += d1; }
    if (base + 2 < N) { offsets[base + 2] = run; cursor[base + 2] = run; dinv[base + 2] = rsqrtf((float)(d2 + 1)); run += d2; }
    if (base + 3 < N) { offsets[base + 3] = run; cursor[base + 3] = run; dinv[base + 3] = rsqrtf((float)(d3 + 1)); run += d3; }
    if (blockIdx.x == 0 && t == 0) offsets[N] = E;
}

// ------------------------------------------------------------------- CSR fill
__global__ __launch_bounds__(256) void fill_kernel(const int* __restrict__ row,
                                                   const int* __restrict__ col,
                                                   int* __restrict__ cursor,
                                                   int* __restrict__ sorted_r, int E) {
    int e = blockIdx.x * 256 + threadIdx.x;
    if (e < E) {
        int c = col[e];
        int p = atomicAdd(&cursor[c], 1);
        sorted_r[p] = row[e];
    }
}

// ---------------------------------------------------- pad x [N,11] -> [N,16]
__global__ __launch_bounds__(256) void pad_x(const float* __restrict__ x,
                                             float* __restrict__ xp, int N) {
    int q = blockIdx.x * 256 + threadIdx.x;
    if (q >= N * 16) return;
    int i = q >> 4, c = q & 15;
    xp[q] = (c < 11) ? x[(size_t)i * 11 + c] : 0.f;
}

// ----------------------------------- aggregate 16-ch padded input (layer 1 pre)
// aggx[c] = dc * ( sum_r dr*xp[r] + dc*xp[c] )   (4 edges/iter, 16 lanes each)
__global__ __launch_bounds__(256) void agg16(const float* __restrict__ xp,
                                             float* __restrict__ aggx,
                                             const int* __restrict__ offsets,
                                             const int* __restrict__ sorted_r,
                                             const float* __restrict__ dinv, int N) {
    int wid  = (blockIdx.x * 256 + threadIdx.x) >> 6;
    int lane = threadIdx.x & 63;
    if (wid >= N) return;
    int c = wid;
    int g = lane >> 4, ch = lane & 15;
    int beg = offsets[c], end = offsets[c + 1];
    float dc = dinv[c];
    float acc = (g == 0) ? dc * xp[(size_t)c * 16 + ch] : 0.f;
    for (int idx = beg + g; idx < end; idx += 4) {
        int r = sorted_r[idx];
        acc += dinv[r] * xp[(size_t)r * 16 + ch];
    }
    acc += __shfl_down(acc, 32);
    acc += __shfl_down(acc, 16);
    if (lane < 16) aggx[(size_t)c * 16 + lane] = acc * dc;
}

// ------------------------------------------- GEMM: bufB = aggx[:, :11] @ W1
__global__ __launch_bounds__(256) void gemm_in_agg(const float* __restrict__ aggx,
                                                   const float* __restrict__ W1,
                                                   float* __restrict__ out, int N) {
    int i = blockIdx.x * 2 + (threadIdx.x >> 7);
    int j = threadIdx.x & 127;
    if (i >= N) return;
    float acc = 0.f;
#pragma unroll
    for (int c = 0; c < 11; ++c) acc += aggx[(size_t)i * 16 + c] * W1[c * HIDDEN + j];
    out[(size_t)i * HIDDEN + j] = acc;
}

// ------------------------------------------------- GEMM: out = relu(H+b) @ W
__global__ __launch_bounds__(256) void gemm128(const float* __restrict__ H,
                                               const float* __restrict__ bias,
                                               const float* __restrict__ W,
                                               float* __restrict__ out, int N) {
    __shared__ float Hlds[16][HIDDEN];   // 8 KB
    int t = threadIdx.x;
    int rowbase = blockIdx.x * 16;
    for (int q = t; q < 16 * HIDDEN; q += 256) {
        int r = q >> 7, k = q & 127;
        int gr = rowbase + r;
        float v = 0.f;
        if (gr < N) v = fmaxf(H[(size_t)gr * HIDDEN + k] + bias[k], 0.f);
        Hlds[r][k] = v;
    }
    __syncthreads();
    int j  = t & 127;
    int rb = t >> 7;
    float acc[8] = {0.f, 0.f, 0.f, 0.f, 0.f, 0.f, 0.f, 0.f};
#pragma unroll 4
    for (int k = 0; k < HIDDEN; ++k) {
        float wv = W[k * HIDDEN + j];
#pragma unroll
        for (int m = 0; m < 8; ++m) acc[m] += Hlds[rb + 2 * m][k] * wv;
    }
#pragma unroll
    for (int m = 0; m < 8; ++m) {
        int gr = rowbase + rb + 2 * m;
        if (gr < N) out[(size_t)gr * HIDDEN + j] = acc[m];
    }
}

// ------------------------- aggregation 128ch: 2 edge rows per dwordx4 gather
// lanes 0-31 = edge A (float4 x 32 = 128 ch), lanes 32-63 = edge B
__global__ __launch_bounds__(256) void agg128(const float* __restrict__ src,
                                              float* __restrict__ dst,
                                              const int* __restrict__ offsets,
                                              const int* __restrict__ sorted_r,
                                              const float* __restrict__ dinv, int N) {
    int wid  = (blockIdx.x * 256 + threadIdx.x) >> 6;
    int lane = threadIdx.x & 63;
    if (wid >= N) return;
    int c = wid;
    int beg = offsets[c], end = offsets[c + 1];
    float dc = dinv[c];
    int half = lane >> 5, sub = lane & 31;
    const float4* srcp = (const float4*)src;
    float4 acc = make_float4(0.f, 0.f, 0.f, 0.f);
    if (half == 0) {
        float4 v = srcp[(size_t)c * 32 + sub];     // self loop
        acc.x = dc * v.x; acc.y = dc * v.y; acc.z = dc * v.z; acc.w = dc * v.w;
    }
    for (int idx = beg + half; idx < end; idx += 2) {
        int r = sorted_r[idx];
        float dr = dinv[r];
        float4 u = srcp[(size_t)r * 32 + sub];
        acc.x += dr * u.x; acc.y += dr * u.y; acc.z += dr * u.z; acc.w += dr * u.w;
    }
    acc.x += __shfl_xor(acc.x, 32);
    acc.y += __shfl_xor(acc.y, 32);
    acc.z += __shfl_xor(acc.z, 32);
    acc.w += __shfl_xor(acc.w, 32);
    if (half == 0) {
        ((float4*)dst)[(size_t)c * 32 + sub] =
            make_float4(acc.x * dc, acc.y * dc, acc.z * dc, acc.w * dc);
    }
}

// --------------------------------------------- pooling stage 1: partial sums
__global__ __launch_bounds__(256) void pool_partial(const float* __restrict__ h,
                                                    const int* __restrict__ batch,
                                                    float* __restrict__ partials, int N) {
    int g = blockIdx.x >> 3, part = blockIdx.x & 7;
    int t = threadIdx.x, j = t & 127, rp = t >> 7;
    int lo = 0, hi = N;
    while (lo < hi) { int m = (lo + hi) >> 1; if (batch[m] < g) lo = m + 1; else hi = m; }
    int beg = lo;
    lo = beg; hi = N;
    while (lo < hi) { int m = (lo + hi) >> 1; if (batch[m] < g + 1) lo = m + 1; else hi = m; }
    int end = lo;
    float acc = 0.f;
    for (int i = beg + part * 2 + rp; i < end; i += 16)
        acc += h[(size_t)i * HIDDEN + j];
    __shared__ float p[2][128];
    p[rp][j] = acc;
    __syncthreads();
    if (rp == 0) partials[(size_t)blockIdx.x * 128 + j] = p[0][j] + p[1][j];
}

// ------------------------------------------------- pooling stage 2 + MLP head
__global__ __launch_bounds__(128) void head_kernel(const float* __restrict__ partials,
                                                   const int* __restrict__ batch,
                                                   const float* __restrict__ b4,
                                                   const float* __restrict__ Wd1,
                                                   const float* __restrict__ bd1,
                                                   const float* __restrict__ Wd2,
                                                   const float* __restrict__ bd2,
                                                   const float* __restrict__ Wo,
                                                   const float* __restrict__ bo,
                                                   float* __restrict__ out, int N) {
    int g = blockIdx.x;
    int j = threadIdx.x;
    __shared__ float sA[128], sB[128], red[128];
    int lo = 0, hi = N;
    while (lo < hi) { int m = (lo + hi) >> 1; if (batch[m] < g) lo = m + 1; else hi = m; }
    int beg = lo;
    lo = beg; hi = N;
    while (lo < hi) { int m = (lo + hi) >> 1; if (batch[m] < g + 1) lo = m + 1; else hi = m; }
    int cnt = lo - beg;
    float s = 0.f;
#pragma unroll
    for (int p = 0; p < 8; ++p) s += partials[(size_t)(g * 8 + p) * 128 + j];
    sA[j] = (cnt > 0) ? s / (float)cnt + b4[j] : 0.f;
    __syncthreads();
    float a = bd1[j];
#pragma unroll 4
    for (int k = 0; k < 128; ++k) a += sA[k] * Wd1[k * HIDDEN + j];
    sB[j] = fmaxf(a, 0.f);
    __syncthreads();
    a = bd2[j];
#pragma unroll 4
    for (int k = 0; k < 128; ++k) a += sB[k] * Wd2[k * HIDDEN + j];
    red[j] = fmaxf(a, 0.f) * Wo[j];
    __syncthreads();
    for (int d = 64; d > 0; d >>= 1) {
        if (j < d) red[j] += red[j + d];
        __syncthreads();
    }
    if (j == 0) out[g] = red[0] + bo[0];
}

// ============================================================================
extern "C" void kernel_launch(void* const* d_in, const int* in_sizes, int n_in,
                              void* d_out, int out_size, void* d_ws, size_t ws_size,
                              hipStream_t stream) {
    const float* x   = (const float*)d_in[0];
    const int*   ei  = (const int*)d_in[1];
    const int*   bat = (const int*)d_in[2];
    const float* W1  = (const float*)d_in[3];
    const float* b1  = (const float*)d_in[4];
    const float* W2  = (const float*)d_in[5];
    const float* b2  = (const float*)d_in[6];
    const float* W4  = (const float*)d_in[7];
    const float* b4  = (const float*)d_in[8];
    const float* Wd1 = (const float*)d_in[9];
    const float* bd1 = (const float*)d_in[10];
    const float* Wd2 = (const float*)d_in[11];
    const float* bd2 = (const float*)d_in[12];
    const float* Wo  = (const float*)d_in[13];
    const float* bo  = (const float*)d_in[14];
    float* out = (float*)d_out;

    const int N = in_sizes[0] / 11;
    const int E = in_sizes[1] / 2;
    const int* row = ei;
    const int* col = ei + E;

    size_t off = 0;
    auto carve = [&](size_t bytes) {
        void* p = (char*)d_ws + off;
        off += (bytes + 255) & ~(size_t)255;
        return p;
    };
    float* bufA     = (float*)carve((size_t)N * HIDDEN * 4);
    float* bufB     = (float*)carve((size_t)N * HIDDEN * 4);
    int*   deg      = (int*)carve((size_t)N * 4);
    int*   offsets  = (int*)carve((size_t)(N + 1) * 4);
    int*   cursor   = (int*)carve((size_t)N * 4);
    float* dinv     = (float*)carve((size_t)N * 4);
    int*   sorted_r = (int*)carve((size_t)E * 4);
    int*   bsums    = (int*)carve((size_t)1024 * 4);
    float* partials = (float*)carve((size_t)128 * 8 * 128 * 4);
    // xp/aggx alias bufA (dead until first gemm128 writes it)
    float* xp   = bufA;
    float* aggx = bufA + (size_t)N * 16;
    (void)ws_size; (void)n_in; (void)out_size;

    // ---- build CSR
    hipMemsetAsync(deg, 0, (size_t)N * 4, stream);
    count_kernel<<<(E + 255) / 256, 256, 0, stream>>>(col, deg, E);
    int scanBlocks = (N + 1023) / 1024;
    scan_blocksums<<<scanBlocks, 256, 0, stream>>>(deg, bsums, N);
    scan_write<<<scanBlocks, 256, 0, stream>>>(deg, bsums, offsets, cursor, dinv, N, E);
    fill_kernel<<<(E + 255) / 256, 256, 0, stream>>>(row, col, cursor, sorted_r, E);

    int aggBlocks  = (N + 3) / 4;
    int gemmBlocks = (N + 15) / 16;

    // ---- layer 1: aggregate 16-ch input FIRST (agg is linear), then GEMM
    pad_x<<<(N * 16 + 255) / 256, 256, 0, stream>>>(x, xp, N);
    agg16<<<aggBlocks, 256, 0, stream>>>(xp, aggx, offsets, sorted_r, dinv, N);
    gemm_in_agg<<<(N + 1) / 2, 256, 0, stream>>>(aggx, W1, bufB, N);
    // ---- layer 2
    gemm128<<<gemmBlocks, 256, 0, stream>>>(bufB, b1, W2, bufA, N);
    agg128<<<aggBlocks, 256, 0, stream>>>(bufA, bufB, offsets, sorted_r, dinv, N);
    // ---- layer 3
    gemm128<<<gemmBlocks, 256, 0, stream>>>(bufB, b2, W4, bufA, N);
    agg128<<<aggBlocks, 256, 0, stream>>>(bufA, bufB, offsets, sorted_r, dinv, N);
    // ---- pool + head
    pool_partial<<<128 * 8, 256, 0, stream>>>(bufB, bat, partials, N);
    head_kernel<<<128, 128, 0, stream>>>(partials, bat, b4, Wd1, bd1, Wd2, bd2,
                                         Wo, bo, out, N);
}

// Round 4
// 681.388 us; speedup vs baseline: 1.8452x; 1.0486x over previous
//
#include <hip/hip_runtime.h>

#define HIDDEN 128

// ---------------------------------------------------------------- degree count
__global__ __launch_bounds__(256) void count_kernel(const int* __restrict__ col,
                                                    int* __restrict__ deg, int E) {
    int e = blockIdx.x * 256 + threadIdx.x;
    if (e < E) atomicAdd(&deg[col[e]], 1);
}

// ----------------------------------------------------- scan phase 1: block sums
__global__ __launch_bounds__(256) void scan_blocksums(const int* __restrict__ deg,
                                                      int* __restrict__ bsums, int N) {
    __shared__ int red[256];
    int t = threadIdx.x;
    int base = blockIdx.x * 1024 + t * 4;
    int s = 0;
    if (base + 3 < N) {
        int4 v = *(const int4*)(deg + base);
        s = v.x + v.y + v.z + v.w;
    } else {
        for (int k = 0; k < 4; ++k) if (base + k < N) s += deg[base + k];
    }
    red[t] = s;
    __syncthreads();
    for (int d = 128; d > 0; d >>= 1) {
        if (t < d) red[t] += red[t + d];
        __syncthreads();
    }
    if (t == 0) bsums[blockIdx.x] = red[0];
}

// ------------------------------------- scan phase 2: write offsets/cursor/dinv
__global__ __launch_bounds__(256) void scan_write(const int* __restrict__ deg,
                                                  const int* __restrict__ bsums,
                                                  int* __restrict__ offsets,
                                                  int* __restrict__ cursor,
                                                  float* __restrict__ dinv,
                                                  int N, int E) {
    __shared__ int incl[256];
    __shared__ int red[256];
    __shared__ int s_boff;
    int t = threadIdx.x;
    int base = blockIdx.x * 1024 + t * 4;
    int d0 = 0, d1 = 0, d2 = 0, d3 = 0;
    if (base + 3 < N) {
        int4 v = *(const int4*)(deg + base);
        d0 = v.x; d1 = v.y; d2 = v.z; d3 = v.w;
    } else {
        if (base + 0 < N) d0 = deg[base + 0];
        if (base + 1 < N) d1 = deg[base + 1];
        if (base + 2 < N) d2 = deg[base + 2];
        if (base + 3 < N) d3 = deg[base + 3];
    }
    int mysum = d0 + d1 + d2 + d3;
    incl[t] = mysum;
    int b = 0;
    for (int i = t; i < blockIdx.x; i += 256) b += bsums[i];
    red[t] = b;
    __syncthreads();
    for (int d = 128; d > 0; d >>= 1) {
        if (t < d) red[t] += red[t + d];
        __syncthreads();
    }
    if (t == 0) s_boff = red[0];
    for (int d = 1; d < 256; d <<= 1) {
        int v = (t >= d) ? incl[t - d] : 0;
        __syncthreads();
        incl[t] += v;
        __syncthreads();
    }
    int run = s_boff + incl[t] - mysum;
    if (base + 0 < N) { offsets[base + 0] = run; cursor[base + 0] = run; dinv[base + 0] = rsqrtf((float)(d0 + 1)); run += d0; }
    if (base + 1 < N) { offsets[base + 1] = run; cursor[base + 1] = run; dinv[base + 1] = rsqrtf((float)(d1 + 1)); run += d1; }
    if (base + 2 < N) { offsets[base + 2] = run; cursor[base + 2] = run; dinv[base + 2] = rsqrtf((float)(d2 + 1)); run += d2; }
    if (base + 3 < N) { offsets[base + 3] = run; cursor[base + 3] = run; dinv[base + 3] = rsqrtf((float)(d3 + 1)); run += d3; }
    if (blockIdx.x == 0 && t == 0) offsets[N] = E;
}

// ----------------------- CSR fill with fused per-edge weight  w = dr*dc
__global__ __launch_bounds__(256) void fill_kernel(const int* __restrict__ row,
                                                   const int* __restrict__ col,
                                                   int* __restrict__ cursor,
                                                   const float* __restrict__ dinv,
                                                   int2* __restrict__ edge_rw, int E) {
    int e = blockIdx.x * 256 + threadIdx.x;
    if (e < E) {
        int c = col[e];
        int r = row[e];
        int p = atomicAdd(&cursor[c], 1);
        float w = dinv[r] * dinv[c];
        edge_rw[p] = make_int2(r, __float_as_int(w));
    }
}

// ---------------------------------------------------- pad x [N,11] -> [N,16]
__global__ __launch_bounds__(256) void pad_x(const float* __restrict__ x,
                                             float* __restrict__ xp, int N) {
    int q = blockIdx.x * 256 + threadIdx.x;
    if (q >= N * 16) return;
    int i = q >> 4, c = q & 15;
    xp[q] = (c < 11) ? x[(size_t)i * 11 + c] : 0.f;
}

// ----------------------------------- aggregate 16-ch padded input (layer 1 pre)
__global__ __launch_bounds__(256) void agg16(const float* __restrict__ xp,
                                             float* __restrict__ aggx,
                                             const int* __restrict__ offsets,
                                             const int2* __restrict__ edge_rw,
                                             const float* __restrict__ dinv, int N) {
    int wid  = (blockIdx.x * 256 + threadIdx.x) >> 6;
    int lane = threadIdx.x & 63;
    if (wid >= N) return;
    int c = wid;
    int g = lane >> 4, ch = lane & 15;
    int beg = offsets[c], end = offsets[c + 1];
    float dc = dinv[c];
    float acc = (g == 0) ? dc * dc * xp[(size_t)c * 16 + ch] : 0.f;
    for (int idx = beg + g; idx < end; idx += 4) {
        int2 q = edge_rw[idx];
        acc += __int_as_float(q.y) * xp[(size_t)q.x * 16 + ch];
    }
    acc += __shfl_down(acc, 32);
    acc += __shfl_down(acc, 16);
    if (lane < 16) aggx[(size_t)c * 16 + lane] = acc;
}

// ------------------------------------------- GEMM: bufB = aggx[:, :11] @ W1
__global__ __launch_bounds__(256) void gemm_in_agg(const float* __restrict__ aggx,
                                                   const float* __restrict__ W1,
                                                   float* __restrict__ out, int N) {
    int i = blockIdx.x * 2 + (threadIdx.x >> 7);
    int j = threadIdx.x & 127;
    if (i >= N) return;
    float acc = 0.f;
#pragma unroll
    for (int c = 0; c < 11; ++c) acc += aggx[(size_t)i * 16 + c] * W1[c * HIDDEN + j];
    out[(size_t)i * HIDDEN + j] = acc;
}

// ------------------------------------------------- GEMM: out = relu(H+b) @ W
__global__ __launch_bounds__(256) void gemm128(const float* __restrict__ H,
                                               const float* __restrict__ bias,
                                               const float* __restrict__ W,
                                               float* __restrict__ out, int N) {
    __shared__ float Hlds[16][HIDDEN];   // 8 KB
    int t = threadIdx.x;
    int rowbase = blockIdx.x * 16;
    for (int q = t; q < 16 * HIDDEN; q += 256) {
        int r = q >> 7, k = q & 127;
        int gr = rowbase + r;
        float v = 0.f;
        if (gr < N) v = fmaxf(H[(size_t)gr * HIDDEN + k] + bias[k], 0.f);
        Hlds[r][k] = v;
    }
    __syncthreads();
    int j  = t & 127;
    int rb = t >> 7;
    float acc[8] = {0.f, 0.f, 0.f, 0.f, 0.f, 0.f, 0.f, 0.f};
#pragma unroll 4
    for (int k = 0; k < HIDDEN; ++k) {
        float wv = W[k * HIDDEN + j];
#pragma unroll
        for (int m = 0; m < 8; ++m) acc[m] += Hlds[rb + 2 * m][k] * wv;
    }
#pragma unroll
    for (int m = 0; m < 8; ++m) {
        int gr = rowbase + rb + 2 * m;
        if (gr < N) out[(size_t)gr * HIDDEN + j] = acc[m];
    }
}

// ---------------- aggregation 128ch: (r,w) pairs + 4-deep pipelined gathers
// half h of the wave handles 4 contiguous edges per main iteration (8/wave-iter)
__global__ __launch_bounds__(256) void agg128(const float* __restrict__ src,
                                              float* __restrict__ dst,
                                              const int* __restrict__ offsets,
                                              const int2* __restrict__ edge_rw,
                                              const float* __restrict__ dinv, int N) {
    int wid  = (blockIdx.x * 256 + threadIdx.x) >> 6;
    int lane = threadIdx.x & 63;
    if (wid >= N) return;
    int c = wid;
    int beg = offsets[c], end = offsets[c + 1];
    float dc = dinv[c];
    int half = lane >> 5, sub = lane & 31;
    const float4* srcp = (const float4*)src;
    float ax = 0.f, ay = 0.f, az = 0.f, aw = 0.f;
    if (half == 0) {
        float4 v = srcp[(size_t)c * 32 + sub];     // self loop, weight dc^2
        float w = dc * dc;
        ax = w * v.x; ay = w * v.y; az = w * v.z; aw = w * v.w;
    }
    int i = beg;
    // main loop: 8 edges per wave-iteration, 4 outstanding gathers per lane
    for (; i + 8 <= end; i += 8) {
        int base = i + 4 * half;
        int2 q0 = edge_rw[base + 0];
        int2 q1 = edge_rw[base + 1];
        int2 q2 = edge_rw[base + 2];
        int2 q3 = edge_rw[base + 3];
        float4 u0 = srcp[(size_t)q0.x * 32 + sub];
        float4 u1 = srcp[(size_t)q1.x * 32 + sub];
        float4 u2 = srcp[(size_t)q2.x * 32 + sub];
        float4 u3 = srcp[(size_t)q3.x * 32 + sub];
        float w0 = __int_as_float(q0.y), w1 = __int_as_float(q1.y);
        float w2 = __int_as_float(q2.y), w3 = __int_as_float(q3.y);
        ax += w0 * u0.x + w1 * u1.x + w2 * u2.x + w3 * u3.x;
        ay += w0 * u0.y + w1 * u1.y + w2 * u2.y + w3 * u3.y;
        az += w0 * u0.z + w1 * u1.z + w2 * u2.z + w3 * u3.z;
        aw += w0 * u0.w + w1 * u1.w + w2 * u2.w + w3 * u3.w;
    }
    // remainder: 2 edges per iteration
    for (; i + half < end; i += 2) {
        int2 q = edge_rw[i + half];
        float w = __int_as_float(q.y);
        float4 u = srcp[(size_t)q.x * 32 + sub];
        ax += w * u.x; ay += w * u.y; az += w * u.z; aw += w * u.w;
    }
    ax += __shfl_xor(ax, 32);
    ay += __shfl_xor(ay, 32);
    az += __shfl_xor(az, 32);
    aw += __shfl_xor(aw, 32);
    if (half == 0) {
        ((float4*)dst)[(size_t)c * 32 + sub] = make_float4(ax, ay, az, aw);
    }
}

// --------------------------------------------- pooling stage 1: partial sums
__global__ __launch_bounds__(256) void pool_partial(const float* __restrict__ h,
                                                    const int* __restrict__ batch,
                                                    float* __restrict__ partials, int N) {
    int g = blockIdx.x >> 3, part = blockIdx.x & 7;
    int t = threadIdx.x, j = t & 127, rp = t >> 7;
    int lo = 0, hi = N;
    while (lo < hi) { int m = (lo + hi) >> 1; if (batch[m] < g) lo = m + 1; else hi = m; }
    int beg = lo;
    lo = beg; hi = N;
    while (lo < hi) { int m = (lo + hi) >> 1; if (batch[m] < g + 1) lo = m + 1; else hi = m; }
    int end = lo;
    float acc = 0.f;
    for (int i = beg + part * 2 + rp; i < end; i += 16)
        acc += h[(size_t)i * HIDDEN + j];
    __shared__ float p[2][128];
    p[rp][j] = acc;
    __syncthreads();
    if (rp == 0) partials[(size_t)blockIdx.x * 128 + j] = p[0][j] + p[1][j];
}

// ------------------------------------------------- pooling stage 2 + MLP head
__global__ __launch_bounds__(128) void head_kernel(const float* __restrict__ partials,
                                                   const int* __restrict__ batch,
                                                   const float* __restrict__ b4,
                                                   const float* __restrict__ Wd1,
                                                   const float* __restrict__ bd1,
                                                   const float* __restrict__ Wd2,
                                                   const float* __restrict__ bd2,
                                                   const float* __restrict__ Wo,
                                                   const float* __restrict__ bo,
                                                   float* __restrict__ out, int N) {
    int g = blockIdx.x;
    int j = threadIdx.x;
    __shared__ float sA[128], sB[128], red[128];
    int lo = 0, hi = N;
    while (lo < hi) { int m = (lo + hi) >> 1; if (batch[m] < g) lo = m + 1; else hi = m; }
    int beg = lo;
    lo = beg; hi = N;
    while (lo < hi) { int m = (lo + hi) >> 1; if (batch[m] < g + 1) lo = m + 1; else hi = m; }
    int cnt = lo - beg;
    float s = 0.f;
#pragma unroll
    for (int p = 0; p < 8; ++p) s += partials[(size_t)(g * 8 + p) * 128 + j];
    sA[j] = (cnt > 0) ? s / (float)cnt + b4[j] : 0.f;
    __syncthreads();
    float a = bd1[j];
#pragma unroll 4
    for (int k = 0; k < 128; ++k) a += sA[k] * Wd1[k * HIDDEN + j];
    sB[j] = fmaxf(a, 0.f);
    __syncthreads();
    a = bd2[j];
#pragma unroll 4
    for (int k = 0; k < 128; ++k) a += sB[k] * Wd2[k * HIDDEN + j];
    red[j] = fmaxf(a, 0.f) * Wo[j];
    __syncthreads();
    for (int d = 64; d > 0; d >>= 1) {
        if (j < d) red[j] += red[j + d];
        __syncthreads();
    }
    if (j == 0) out[g] = red[0] + bo[0];
}

// ============================================================================
extern "C" void kernel_launch(void* const* d_in, const int* in_sizes, int n_in,
                              void* d_out, int out_size, void* d_ws, size_t ws_size,
                              hipStream_t stream) {
    const float* x   = (const float*)d_in[0];
    const int*   ei  = (const int*)d_in[1];
    const int*   bat = (const int*)d_in[2];
    const float* W1  = (const float*)d_in[3];
    const float* b1  = (const float*)d_in[4];
    const float* W2  = (const float*)d_in[5];
    const float* b2  = (const float*)d_in[6];
    const float* W4  = (const float*)d_in[7];
    const float* b4  = (const float*)d_in[8];
    const float* Wd1 = (const float*)d_in[9];
    const float* bd1 = (const float*)d_in[10];
    const float* Wd2 = (const float*)d_in[11];
    const float* bd2 = (const float*)d_in[12];
    const float* Wo  = (const float*)d_in[13];
    const float* bo  = (const float*)d_in[14];
    float* out = (float*)d_out;

    const int N = in_sizes[0] / 11;
    const int E = in_sizes[1] / 2;
    const int* row = ei;
    const int* col = ei + E;

    size_t off = 0;
    auto carve = [&](size_t bytes) {
        void* p = (char*)d_ws + off;
        off += (bytes + 255) & ~(size_t)255;
        return p;
    };
    float* bufA     = (float*)carve((size_t)N * HIDDEN * 4);
    float* bufB     = (float*)carve((size_t)N * HIDDEN * 4);
    int*   deg      = (int*)carve((size_t)N * 4);
    int*   offsets  = (int*)carve((size_t)(N + 1) * 4);
    int*   cursor   = (int*)carve((size_t)N * 4);
    float* dinv     = (float*)carve((size_t)N * 4);
    int2*  edge_rw  = (int2*)carve((size_t)E * 8);
    int*   bsums    = (int*)carve((size_t)1024 * 4);
    float* partials = (float*)carve((size_t)128 * 8 * 128 * 4);
    // xp/aggx alias bufA (dead until first gemm128 writes it)
    float* xp   = bufA;
    float* aggx = bufA + (size_t)N * 16;
    (void)ws_size; (void)n_in; (void)out_size;

    // ---- build CSR
    hipMemsetAsync(deg, 0, (size_t)N * 4, stream);
    count_kernel<<<(E + 255) / 256, 256, 0, stream>>>(col, deg, E);
    int scanBlocks = (N + 1023) / 1024;
    scan_blocksums<<<scanBlocks, 256, 0, stream>>>(deg, bsums, N);
    scan_write<<<scanBlocks, 256, 0, stream>>>(deg, bsums, offsets, cursor, dinv, N, E);
    fill_kernel<<<(E + 255) / 256, 256, 0, stream>>>(row, col, cursor, dinv, edge_rw, E);

    int aggBlocks  = (N + 3) / 4;
    int gemmBlocks = (N + 15) / 16;

    // ---- layer 1: aggregate 16-ch input FIRST (agg is linear), then GEMM
    pad_x<<<(N * 16 + 255) / 256, 256, 0, stream>>>(x, xp, N);
    agg16<<<aggBlocks, 256, 0, stream>>>(xp, aggx, offsets, edge_rw, dinv, N);
    gemm_in_agg<<<(N + 1) / 2, 256, 0, stream>>>(aggx, W1, bufB, N);
    // ---- layer 2
    gemm128<<<gemmBlocks, 256, 0, stream>>>(bufB, b1, W2, bufA, N);
    agg128<<<aggBlocks, 256, 0, stream>>>(bufA, bufB, offsets, edge_rw, dinv, N);
    // ---- layer 3
    gemm128<<<gemmBlocks, 256, 0, stream>>>(bufB, b2, W4, bufA, N);
    agg128<<<aggBlocks, 256, 0, stream>>>(bufA, bufB, offsets, edge_rw, dinv, N);
    // ---- pool + head
    pool_partial<<<128 * 8, 256, 0, stream>>>(bufB, bat, partials, N);
    head_kernel<<<128, 128, 0, stream>>>(partials, bat, b4, Wd1, bd1, Wd2, bd2,
                                         Wo, bo, out, N);
}

// Round 5
// 548.286 us; speedup vs baseline: 2.2931x; 1.2428x over previous
//
#include <hip/hip_runtime.h>
#include <hip/hip_fp16.h>

#define HIDDEN 128

// ---------------------------------------------------------------- degree count
__global__ __launch_bounds__(256) void count_kernel(const int* __restrict__ col,
                                                    int* __restrict__ deg, int E) {
    int e = blockIdx.x * 256 + threadIdx.x;
    if (e < E) atomicAdd(&deg[col[e]], 1);
}

// ----------------------------------------------------- scan phase 1: block sums
__global__ __launch_bounds__(256) void scan_blocksums(const int* __restrict__ deg,
                                                      int* __restrict__ bsums, int N) {
    __shared__ int red[256];
    int t = threadIdx.x;
    int base = blockIdx.x * 1024 + t * 4;
    int s = 0;
    if (base + 3 < N) {
        int4 v = *(const int4*)(deg + base);
        s = v.x + v.y + v.z + v.w;
    } else {
        for (int k = 0; k < 4; ++k) if (base + k < N) s += deg[base + k];
    }
    red[t] = s;
    __syncthreads();
    for (int d = 128; d > 0; d >>= 1) {
        if (t < d) red[t] += red[t + d];
        __syncthreads();
    }
    if (t == 0) bsums[blockIdx.x] = red[0];
}

// ------------------------------------- scan phase 2: write offsets/cursor/dinv
__global__ __launch_bounds__(256) void scan_write(const int* __restrict__ deg,
                                                  const int* __restrict__ bsums,
                                                  int* __restrict__ offsets,
                                                  int* __restrict__ cursor,
                                                  float* __restrict__ dinv,
                                                  int N, int E) {
    __shared__ int incl[256];
    __shared__ int red[256];
    __shared__ int s_boff;
    int t = threadIdx.x;
    int base = blockIdx.x * 1024 + t * 4;
    int d0 = 0, d1 = 0, d2 = 0, d3 = 0;
    if (base + 3 < N) {
        int4 v = *(const int4*)(deg + base);
        d0 = v.x; d1 = v.y; d2 = v.z; d3 = v.w;
    } else {
        if (base + 0 < N) d0 = deg[base + 0];
        if (base + 1 < N) d1 = deg[base + 1];
        if (base + 2 < N) d2 = deg[base + 2];
        if (base + 3 < N) d3 = deg[base + 3];
    }
    int mysum = d0 + d1 + d2 + d3;
    incl[t] = mysum;
    int b = 0;
    for (int i = t; i < blockIdx.x; i += 256) b += bsums[i];
    red[t] = b;
    __syncthreads();
    for (int d = 128; d > 0; d >>= 1) {
        if (t < d) red[t] += red[t + d];
        __syncthreads();
    }
    if (t == 0) s_boff = red[0];
    for (int d = 1; d < 256; d <<= 1) {
        int v = (t >= d) ? incl[t - d] : 0;
        __syncthreads();
        incl[t] += v;
        __syncthreads();
    }
    int run = s_boff + incl[t] - mysum;
    if (base + 0 < N) { offsets[base + 0] = run; cursor[base + 0] = run; dinv[base + 0] = rsqrtf((float)(d0 + 1)); run += d0; }
    if (base + 1 < N) { offsets[base + 1] = run; cursor[base + 1] = run; dinv[base + 1] = rsqrtf((float)(d1 + 1)); run += d1; }
    if (base + 2 < N) { offsets[base + 2] = run; cursor[base + 2] = run; dinv[base + 2] = rsqrtf((float)(d2 + 1)); run += d2; }
    if (base + 3 < N) { offsets[base + 3] = run; cursor[base + 3] = run; dinv[base + 3] = rsqrtf((float)(d3 + 1)); run += d3; }
    if (blockIdx.x == 0 && t == 0) offsets[N] = E;
}

// ----------------------- CSR fill with fused per-edge weight  w = dr*dc
__global__ __launch_bounds__(256) void fill_kernel(const int* __restrict__ row,
                                                   const int* __restrict__ col,
                                                   int* __restrict__ cursor,
                                                   const float* __restrict__ dinv,
                                                   int2* __restrict__ edge_rw, int E) {
    int e = blockIdx.x * 256 + threadIdx.x;
    if (e < E) {
        int c = col[e];
        int r = row[e];
        int p = atomicAdd(&cursor[c], 1);
        float w = dinv[r] * dinv[c];
        edge_rw[p] = make_int2(r, __float_as_int(w));
    }
}

// ------------------------------------------- pad x [N,11] -> fp16 [N,16]
__global__ __launch_bounds__(256) void pad_x(const float* __restrict__ x,
                                             __half* __restrict__ xp, int N) {
    int q = blockIdx.x * 256 + threadIdx.x;
    if (q >= N * 16) return;
    int i = q >> 4, c = q & 15;
    xp[q] = __float2half((c < 11) ? x[(size_t)i * 11 + c] : 0.f);
}

// ----------------------------------- aggregate 16-ch padded input (layer 1 pre)
__global__ __launch_bounds__(256) void agg16(const __half* __restrict__ xp,
                                             float* __restrict__ aggx,
                                             const int* __restrict__ offsets,
                                             const int2* __restrict__ edge_rw,
                                             const float* __restrict__ dinv, int N) {
    int wid  = (blockIdx.x * 256 + threadIdx.x) >> 6;
    int lane = threadIdx.x & 63;
    if (wid >= N) return;
    int c = wid;
    int g = lane >> 4, ch = lane & 15;
    int beg = offsets[c], end = offsets[c + 1];
    float dc = dinv[c];
    float acc = (g == 0) ? dc * dc * __half2float(xp[(size_t)c * 16 + ch]) : 0.f;
    for (int idx = beg + g; idx < end; idx += 4) {
        int2 q = edge_rw[idx];
        acc += __int_as_float(q.y) * __half2float(xp[(size_t)q.x * 16 + ch]);
    }
    acc += __shfl_down(acc, 32);
    acc += __shfl_down(acc, 16);
    if (lane < 16) aggx[(size_t)c * 16 + lane] = acc;
}

// ------------------------------------------- GEMM: h1 = aggx[:, :11] @ W1 (fp32)
__global__ __launch_bounds__(256) void gemm_in_agg(const float* __restrict__ aggx,
                                                   const float* __restrict__ W1,
                                                   float* __restrict__ out, int N) {
    int i = blockIdx.x * 2 + (threadIdx.x >> 7);
    int j = threadIdx.x & 127;
    if (i >= N) return;
    float acc = 0.f;
#pragma unroll
    for (int c = 0; c < 11; ++c) acc += aggx[(size_t)i * 16 + c] * W1[c * HIDDEN + j];
    out[(size_t)i * HIDDEN + j] = acc;
}

// --------------------------- GEMM: out_fp16 = relu(H+b) @ W  (fp32 accumulate)
__global__ __launch_bounds__(256) void gemm128(const float* __restrict__ H,
                                               const float* __restrict__ bias,
                                               const float* __restrict__ W,
                                               __half* __restrict__ out, int N) {
    __shared__ float Hlds[16][HIDDEN];   // 8 KB
    int t = threadIdx.x;
    int rowbase = blockIdx.x * 16;
    for (int q = t; q < 16 * HIDDEN; q += 256) {
        int r = q >> 7, k = q & 127;
        int gr = rowbase + r;
        float v = 0.f;
        if (gr < N) v = fmaxf(H[(size_t)gr * HIDDEN + k] + bias[k], 0.f);
        Hlds[r][k] = v;
    }
    __syncthreads();
    int j  = t & 127;
    int rb = t >> 7;
    float acc[8] = {0.f, 0.f, 0.f, 0.f, 0.f, 0.f, 0.f, 0.f};
#pragma unroll 4
    for (int k = 0; k < HIDDEN; ++k) {
        float wv = W[k * HIDDEN + j];
#pragma unroll
        for (int m = 0; m < 8; ++m) acc[m] += Hlds[rb + 2 * m][k] * wv;
    }
#pragma unroll
    for (int m = 0; m < 8; ++m) {
        int gr = rowbase + rb + 2 * m;
        if (gr < N) out[(size_t)gr * HIDDEN + j] = __float2half(acc[m]);
    }
}

// -------- aggregation 128ch fp16: 16 lanes/edge (uint4 = 8 halves per lane),
//          4 edge-groups per wave, 4-deep unrolled main loop (16 edges/iter)
__global__ __launch_bounds__(256) void agg128h(const __half* __restrict__ src,
                                               float* __restrict__ dst,
                                               const int* __restrict__ offsets,
                                               const int2* __restrict__ edge_rw,
                                               const float* __restrict__ dinv, int N) {
    int wid  = (blockIdx.x * 256 + threadIdx.x) >> 6;
    int lane = threadIdx.x & 63;
    if (wid >= N) return;
    int c = wid;
    int beg = offsets[c], end = offsets[c + 1];
    float dc = dinv[c];
    int g = lane >> 4, sub = lane & 15;
    const uint4* hp = (const uint4*)src;          // 16 B = 8 halves per element
    float a0=0.f,a1=0.f,a2=0.f,a3=0.f,a4=0.f,a5=0.f,a6=0.f,a7=0.f;

    auto accum = [&](uint4 u, float w) {
        __half2 p0 = *(__half2*)&u.x, p1 = *(__half2*)&u.y;
        __half2 p2 = *(__half2*)&u.z, p3 = *(__half2*)&u.w;
        float2 f0 = __half22float2(p0), f1 = __half22float2(p1);
        float2 f2 = __half22float2(p2), f3 = __half22float2(p3);
        a0 += w * f0.x; a1 += w * f0.y; a2 += w * f1.x; a3 += w * f1.y;
        a4 += w * f2.x; a5 += w * f2.y; a6 += w * f3.x; a7 += w * f3.y;
    };

    if (g == 0) accum(hp[(size_t)c * 16 + sub], dc * dc);   // self loop

    int i = beg;
    for (; i + 16 <= end; i += 16) {              // 4 edges per group
        int base = i + 4 * g;
        int2 q0 = edge_rw[base + 0];
        int2 q1 = edge_rw[base + 1];
        int2 q2 = edge_rw[base + 2];
        int2 q3 = edge_rw[base + 3];
        uint4 u0 = hp[(size_t)q0.x * 16 + sub];
        uint4 u1 = hp[(size_t)q1.x * 16 + sub];
        uint4 u2 = hp[(size_t)q2.x * 16 + sub];
        uint4 u3 = hp[(size_t)q3.x * 16 + sub];
        accum(u0, __int_as_float(q0.y));
        accum(u1, __int_as_float(q1.y));
        accum(u2, __int_as_float(q2.y));
        accum(u3, __int_as_float(q3.y));
    }
    for (int idx = i + g; idx < end; idx += 4) {  // remainder, 1 edge per group
        int2 q = edge_rw[idx];
        accum(hp[(size_t)q.x * 16 + sub], __int_as_float(q.y));
    }
    // reduce across the 4 groups (lanes with same sub)
    a0 += __shfl_xor(a0, 32); a1 += __shfl_xor(a1, 32);
    a2 += __shfl_xor(a2, 32); a3 += __shfl_xor(a3, 32);
    a4 += __shfl_xor(a4, 32); a5 += __shfl_xor(a5, 32);
    a6 += __shfl_xor(a6, 32); a7 += __shfl_xor(a7, 32);
    a0 += __shfl_xor(a0, 16); a1 += __shfl_xor(a1, 16);
    a2 += __shfl_xor(a2, 16); a3 += __shfl_xor(a3, 16);
    a4 += __shfl_xor(a4, 16); a5 += __shfl_xor(a5, 16);
    a6 += __shfl_xor(a6, 16); a7 += __shfl_xor(a7, 16);
    if (g == 0) {
        float4* dp = (float4*)(dst + (size_t)c * HIDDEN + sub * 8);
        dp[0] = make_float4(a0, a1, a2, a3);
        dp[1] = make_float4(a4, a5, a6, a7);
    }
}

// --------------------------------------------- pooling stage 1: partial sums
__global__ __launch_bounds__(256) void pool_partial(const float* __restrict__ h,
                                                    const int* __restrict__ batch,
                                                    float* __restrict__ partials, int N) {
    int g = blockIdx.x >> 3, part = blockIdx.x & 7;
    int t = threadIdx.x, j = t & 127, rp = t >> 7;
    int lo = 0, hi = N;
    while (lo < hi) { int m = (lo + hi) >> 1; if (batch[m] < g) lo = m + 1; else hi = m; }
    int beg = lo;
    lo = beg; hi = N;
    while (lo < hi) { int m = (lo + hi) >> 1; if (batch[m] < g + 1) lo = m + 1; else hi = m; }
    int end = lo;
    float acc = 0.f;
    for (int i = beg + part * 2 + rp; i < end; i += 16)
        acc += h[(size_t)i * HIDDEN + j];
    __shared__ float p[2][128];
    p[rp][j] = acc;
    __syncthreads();
    if (rp == 0) partials[(size_t)blockIdx.x * 128 + j] = p[0][j] + p[1][j];
}

// ------------------------------------------------- pooling stage 2 + MLP head
__global__ __launch_bounds__(128) void head_kernel(const float* __restrict__ partials,
                                                   const int* __restrict__ batch,
                                                   const float* __restrict__ b4,
                                                   const float* __restrict__ Wd1,
                                                   const float* __restrict__ bd1,
                                                   const float* __restrict__ Wd2,
                                                   const float* __restrict__ bd2,
                                                   const float* __restrict__ Wo,
                                                   const float* __restrict__ bo,
                                                   float* __restrict__ out, int N) {
    int g = blockIdx.x;
    int j = threadIdx.x;
    __shared__ float sA[128], sB[128], red[128];
    int lo = 0, hi = N;
    while (lo < hi) { int m = (lo + hi) >> 1; if (batch[m] < g) lo = m + 1; else hi = m; }
    int beg = lo;
    lo = beg; hi = N;
    while (lo < hi) { int m = (lo + hi) >> 1; if (batch[m] < g + 1) lo = m + 1; else hi = m; }
    int cnt = lo - beg;
    float s = 0.f;
#pragma unroll
    for (int p = 0; p < 8; ++p) s += partials[(size_t)(g * 8 + p) * 128 + j];
    sA[j] = (cnt > 0) ? s / (float)cnt + b4[j] : 0.f;
    __syncthreads();
    float a = bd1[j];
#pragma unroll 4
    for (int k = 0; k < 128; ++k) a += sA[k] * Wd1[k * HIDDEN + j];
    sB[j] = fmaxf(a, 0.f);
    __syncthreads();
    a = bd2[j];
#pragma unroll 4
    for (int k = 0; k < 128; ++k) a += sB[k] * Wd2[k * HIDDEN + j];
    red[j] = fmaxf(a, 0.f) * Wo[j];
    __syncthreads();
    for (int d = 64; d > 0; d >>= 1) {
        if (j < d) red[j] += red[j + d];
        __syncthreads();
    }
    if (j == 0) out[g] = red[0] + bo[0];
}

// ============================================================================
extern "C" void kernel_launch(void* const* d_in, const int* in_sizes, int n_in,
                              void* d_out, int out_size, void* d_ws, size_t ws_size,
                              hipStream_t stream) {
    const float* x   = (const float*)d_in[0];
    const int*   ei  = (const int*)d_in[1];
    const int*   bat = (const int*)d_in[2];
    const float* W1  = (const float*)d_in[3];
    const float* b1  = (const float*)d_in[4];
    const float* W2  = (const float*)d_in[5];
    const float* b2  = (const float*)d_in[6];
    const float* W4  = (const float*)d_in[7];
    const float* b4  = (const float*)d_in[8];
    const float* Wd1 = (const float*)d_in[9];
    const float* bd1 = (const float*)d_in[10];
    const float* Wd2 = (const float*)d_in[11];
    const float* bd2 = (const float*)d_in[12];
    const float* Wo  = (const float*)d_in[13];
    const float* bo  = (const float*)d_in[14];
    float* out = (float*)d_out;

    const int N = in_sizes[0] / 11;
    const int E = in_sizes[1] / 2;
    const int* row = ei;
    const int* col = ei + E;

    size_t off = 0;
    auto carve = [&](size_t bytes) {
        void* p = (char*)d_ws + off;
        off += (bytes + 255) & ~(size_t)255;
        return p;
    };
    float*  bufB     = (float*)carve((size_t)N * HIDDEN * 4);   // fp32 ping
    __half* bufH     = (__half*)carve((size_t)N * HIDDEN * 2);  // fp16 gather src
    __half* xp       = (__half*)carve((size_t)N * 16 * 2);
    float*  aggx     = (float*)carve((size_t)N * 16 * 4);
    int*    deg      = (int*)carve((size_t)N * 4);
    int*    offsets  = (int*)carve((size_t)(N + 1) * 4);
    int*    cursor   = (int*)carve((size_t)N * 4);
    float*  dinv     = (float*)carve((size_t)N * 4);
    int2*   edge_rw  = (int2*)carve((size_t)E * 8);
    int*    bsums    = (int*)carve((size_t)1024 * 4);
    float*  partials = (float*)carve((size_t)128 * 8 * 128 * 4);
    (void)ws_size; (void)n_in; (void)out_size;

    // ---- build CSR
    hipMemsetAsync(deg, 0, (size_t)N * 4, stream);
    count_kernel<<<(E + 255) / 256, 256, 0, stream>>>(col, deg, E);
    int scanBlocks = (N + 1023) / 1024;
    scan_blocksums<<<scanBlocks, 256, 0, stream>>>(deg, bsums, N);
    scan_write<<<scanBlocks, 256, 0, stream>>>(deg, bsums, offsets, cursor, dinv, N, E);
    fill_kernel<<<(E + 255) / 256, 256, 0, stream>>>(row, col, cursor, dinv, edge_rw, E);

    int aggBlocks  = (N + 3) / 4;
    int gemmBlocks = (N + 15) / 16;

    // ---- layer 1: aggregate 16-ch fp16 input FIRST (agg is linear), then GEMM
    pad_x<<<(N * 16 + 255) / 256, 256, 0, stream>>>(x, xp, N);
    agg16<<<aggBlocks, 256, 0, stream>>>(xp, aggx, offsets, edge_rw, dinv, N);
    gemm_in_agg<<<(N + 1) / 2, 256, 0, stream>>>(aggx, W1, bufB, N);
    // ---- layer 2: gemm fp32->fp16, gather fp16 -> fp32
    gemm128<<<gemmBlocks, 256, 0, stream>>>(bufB, b1, W2, bufH, N);
    agg128h<<<aggBlocks, 256, 0, stream>>>(bufH, bufB, offsets, edge_rw, dinv, N);
    // ---- layer 3
    gemm128<<<gemmBlocks, 256, 0, stream>>>(bufB, b2, W4, bufH, N);
    agg128h<<<aggBlocks, 256, 0, stream>>>(bufH, bufB, offsets, edge_rw, dinv, N);
    // ---- pool + head
    pool_partial<<<128 * 8, 256, 0, stream>>>(bufB, bat, partials, N);
    head_kernel<<<128, 128, 0, stream>>>(partials, bat, b4, Wd1, bd1, Wd2, bd2,
                                         Wo, bo, out, N);
}